// Round 2
// baseline (103.068 us; speedup 1.0000x reference)
//
#include <hip/hip_runtime.h>

#define C 161
#define C3 4173281           // 161^3 dual vertices (cells)
#define NVERT_ELEMS 12519843 // C3*3
#define APQ 4121600          // 161*160*160 quads per axis
#define TQ 12364800          // 3*APQ

// round f32 to nearest bf16 (RNE), return as f32
__device__ __forceinline__ float bf16r(float f) {
    union { float f; unsigned int u; } v; v.f = f;
    v.u += 0x7FFFu + ((v.u >> 16) & 1u);
    v.u &= 0xFFFF0000u;
    return v.f;
}

// g = pad(grid, 1, constant=1.0); point coords x,y,z in [0,162)
__device__ __forceinline__ float sampg(const float* __restrict__ g, int x, int y, int z) {
    unsigned ux = (unsigned)(x - 1), uy = (unsigned)(y - 1), uz = (unsigned)(z - 1);
    if (ux >= 160u || uy >= 160u || uz >= 160u) return 1.0f;
    return g[(ux * 160u + uy) * 160u + uz];
}

__global__ __launch_bounds__(256) void verts_kernel(const float* __restrict__ grid,
                                                    const float* __restrict__ deform,
                                                    float* __restrict__ out) {
    int tid = blockIdx.x * blockDim.x + threadIdx.x;
    if (tid >= C3) return;
    int cz = tid % C;
    int t  = tid / C;
    int cy = t % C;
    int cx = t / C;

    float gv[8], px[8], py[8], pz[8];
#pragma unroll
    for (int c = 0; c < 8; ++c) {
        int bx = (c >> 2) & 1, by = (c >> 1) & 1, bz = c & 1;
        int x = cx + bx, y = cy + by, z = cz + bz;
        gv[c] = sampg(grid, x, y, z);
        float dx = 0.f, dy = 0.f, dz = 0.f;
        unsigned ux = (unsigned)(x - 1), uy = (unsigned)(y - 1), uz = (unsigned)(z - 1);
        if (ux < 160u && uy < 160u && uz < 160u) {
            const float* p = deform + ((size_t)((ux * 160u + uy) * 160u + uz)) * 3;
            dx = p[0]; dy = p[1]; dz = p[2];
        }
        px[c] = (float)x + dx;
        py[c] = (float)y + dy;
        pz[c] = (float)z + dz;
    }

    float vs0 = 0.f, vs1 = 0.f, vs2 = 0.f, cnt = 0.f;
#pragma unroll
    for (int a = 0; a < 3; ++a) {
        int step = (a == 0) ? 4 : ((a == 1) ? 2 : 1);
#pragma unroll
        for (int c = 0; c < 8; ++c) {
            if (c & step) continue;
            int c1 = c | step;
            float g0 = gv[c], g1 = gv[c1];
            if ((g0 < 0.f) != (g1 < 0.f)) {
                float tt = g0 / (g0 - g1);
                vs0 += px[c] + tt * (px[c1] - px[c]);
                vs1 += py[c] + tt * (py[c1] - py[c]);
                vs2 += pz[c] + tt * (pz[c1] - pz[c]);
                cnt += 1.f;
            }
        }
    }

    float v0, v1, v2;
    if (cnt > 0.f) {
        float inv = 1.f / cnt;
        v0 = vs0 * inv; v1 = vs1 * inv; v2 = vs2 * inv;
    } else {
        v0 = v1 = v2 = 0.f;
    }
    const float s = 1.0f / 159.0f;
    int o = tid * 3;
    out[o + 0] = bf16r((v0 - 1.f) * s);
    out[o + 1] = bf16r((v1 - 1.f) * s);
    out[o + 2] = bf16r((v2 - 1.f) * s);
}

__global__ __launch_bounds__(256) void quads_kernel(const float* __restrict__ grid,
                                                    float* __restrict__ out) {
    int tid = blockIdx.x * blockDim.x + threadIdx.x;
    if (tid >= TQ) return;
    int a = tid / APQ;
    int rem = tid - a * APQ;

    int ex, ey, ez;
    int q0, q1, q2, q3;
    float g0, g1;
    if (a == 0) {
        int i2 = rem % 160; int r = rem / 160; int i1 = r % 160; int i0 = r / 160;
        ex = i0; ey = i1 + 1; ez = i2 + 1;
        g0 = sampg(grid, ex, ey, ez);
        g1 = sampg(grid, ex + 1, ey, ez);
        int b = (ex * C + ey) * C + ez;
        q0 = b - C - 1;      // (ex, ey-1, ez-1)
        q1 = b - 1;          // (ex, ey,   ez-1)
        q2 = b;              // (ex, ey,   ez)
        q3 = b - C;          // (ex, ey-1, ez)
    } else if (a == 1) {
        int i2 = rem % 160; int r = rem / 160; int i1 = r % 161; int i0 = r / 161;
        ex = i0 + 1; ey = i1; ez = i2 + 1;
        g0 = sampg(grid, ex, ey, ez);
        g1 = sampg(grid, ex, ey + 1, ez);
        int b = (ex * C + ey) * C + ez;
        q0 = b - C * C - 1;  // (ex-1, ey, ez-1)
        q1 = b - 1;          // (ex,   ey, ez-1)
        q2 = b;              // (ex,   ey, ez)
        q3 = b - C * C;      // (ex-1, ey, ez)
    } else {
        int i2 = rem % 161; int r = rem / 161; int i1 = r % 160; int i0 = r / 160;
        ex = i0 + 1; ey = i1 + 1; ez = i2;
        g0 = sampg(grid, ex, ey, ez);
        g1 = sampg(grid, ex, ey, ez + 1);
        int b = (ex * C + ey) * C + ez;
        q0 = b - C * C - C;  // (ex-1, ey-1, ez)
        q1 = b - C;          // (ex,   ey-1, ez)
        q2 = b;              // (ex,   ey,   ez)
        q3 = b - C * C;      // (ex-1, ey,   ez)
    }

    float w0, w1, w2, w3;
    bool m = (g0 < 0.f) != (g1 < 0.f);
    if (!m) {
        w0 = w1 = w2 = w3 = -1.0f;
    } else {
        int a0, a1, a2, a3;
        if (g0 < 0.f) { a0 = q0; a1 = q1; a2 = q2; a3 = q3; }
        else          { a0 = q3; a1 = q2; a2 = q1; a3 = q0; }
        w0 = bf16r((float)a0);
        w1 = bf16r((float)a1);
        w2 = bf16r((float)a2);
        w3 = bf16r((float)a3);
    }
    float* p = out + NVERT_ELEMS + (size_t)tid * 4;
    p[0] = w0; p[1] = w1; p[2] = w2; p[3] = w3;
}

extern "C" void kernel_launch(void* const* d_in, const int* in_sizes, int n_in,
                              void* d_out, int out_size, void* d_ws, size_t ws_size,
                              hipStream_t stream) {
    const float* grid   = (const float*)d_in[0];
    const float* deform = (const float*)d_in[1];
    float* out = (float*)d_out;

    int nvb = (C3 + 255) / 256;
    hipLaunchKernelGGL(verts_kernel, dim3(nvb), dim3(256), 0, stream, grid, deform, out);

    int nqb = (TQ + 255) / 256;
    hipLaunchKernelGGL(quads_kernel, dim3(nqb), dim3(256), 0, stream, grid, out);
}

// Round 3
// 86.970 us; speedup vs baseline: 1.1851x; 1.1851x over previous
//
#include <hip/hip_runtime.h>

#define C 161
#define C3 4173281            // 161^3 dual vertices (cells)
#define NVERT_ELEMS 12519843  // C3*3
#define APQ 4121600           // 161*160*160 quads per axis
#define TQ 12364800           // 3*APQ
#define TOTQ_ELEMS 49459200   // 4*TQ

// round f32 to nearest bf16 (RNE), return as f32
__device__ __forceinline__ float bf16r(float f) {
    union { float f; unsigned int u; } v; v.f = f;
    v.u += 0x7FFFu + ((v.u >> 16) & 1u);
    v.u &= 0xFFFF0000u;
    return v.f;
}

// branchless sample of padded grid (pad value 1.0); x,y,z in padded coords
__device__ __forceinline__ float sampg(const float* __restrict__ g, int x, int y, int z) {
    int ux = x - 1, uy = y - 1, uz = z - 1;
    bool in = ((unsigned)ux < 160u) && ((unsigned)uy < 160u) && ((unsigned)uz < 160u);
    int cx = min(max(ux, 0), 159);
    int cy = min(max(uy, 0), 159);
    int cz = min(max(uz, 0), 159);
    float v = g[(cx * 160 + cy) * 160 + cz];
    return in ? v : 1.0f;
}

__global__ __launch_bounds__(256) void verts_kernel(const float* __restrict__ grid,
                                                    const float* __restrict__ deform,
                                                    float* __restrict__ out) {
    __shared__ __align__(16) float sv[768];
    int tid = blockIdx.x * 256 + threadIdx.x;
    int cz = tid % C;
    int t2 = tid / C;
    int cy = t2 % C;
    int cx = t2 / C;

    float gv[8], px[8], py[8], pz[8];
#pragma unroll
    for (int c = 0; c < 8; ++c) {
        int bx = (c >> 2) & 1, by = (c >> 1) & 1, bz = c & 1;
        int x = cx + bx, y = cy + by, z = cz + bz;
        gv[c] = sampg(grid, x, y, z);
        int ux = x - 1, uy = y - 1, uz = z - 1;
        bool in = ((unsigned)ux < 160u) && ((unsigned)uy < 160u) && ((unsigned)uz < 160u);
        int ix = min(max(ux, 0), 159);
        int iy = min(max(uy, 0), 159);
        int iz = min(max(uz, 0), 159);
        const float* p = deform + ((size_t)((ix * 160 + iy) * 160 + iz)) * 3;
        float dx = p[0], dy = p[1], dz = p[2];
        px[c] = (float)x + (in ? dx : 0.f);
        py[c] = (float)y + (in ? dy : 0.f);
        pz[c] = (float)z + (in ? dz : 0.f);
    }

    float vs0 = 0.f, vs1 = 0.f, vs2 = 0.f, cnt = 0.f;
#pragma unroll
    for (int a = 0; a < 3; ++a) {
        int step = (a == 0) ? 4 : ((a == 1) ? 2 : 1);
#pragma unroll
        for (int c = 0; c < 8; ++c) {
            if (c & step) continue;
            int c1 = c | step;
            float g0 = gv[c], g1 = gv[c1];
            if ((g0 < 0.f) != (g1 < 0.f)) {
                float tt = g0 * __builtin_amdgcn_rcpf(g0 - g1);
                vs0 += px[c] + tt * (px[c1] - px[c]);
                vs1 += py[c] + tt * (py[c1] - py[c]);
                vs2 += pz[c] + tt * (pz[c1] - pz[c]);
                cnt += 1.f;
            }
        }
    }

    float v0, v1, v2;
    if (cnt > 0.f) {
        float inv = __builtin_amdgcn_rcpf(cnt);   // cnt in {1..12}, exact-ish; bf16 hides 1ulp
        v0 = vs0 * inv; v1 = vs1 * inv; v2 = vs2 * inv;
    } else {
        v0 = v1 = v2 = 0.f;
    }
    const float s = 1.0f / 159.0f;
    int lt = threadIdx.x * 3;
    sv[lt + 0] = bf16r((v0 - 1.f) * s);
    sv[lt + 1] = bf16r((v1 - 1.f) * s);
    sv[lt + 2] = bf16r((v2 - 1.f) * s);

    __syncthreads();
    int base = blockIdx.x * 768;
    int lim = NVERT_ELEMS - base;
    if (lim > 768) lim = 768;
    int off = threadIdx.x << 2;
    if (off + 4 <= lim) {
        float4 v = *(const float4*)&sv[off];
        *(float4*)(out + base + off) = v;
    } else if (off < lim) {
        for (int k = off; k < lim; ++k) out[base + k] = sv[k];
    }
}

// full quad values (w0..w3 = elements 0..3, bf16-rounded floats) for quad q
__device__ __forceinline__ float4 quad_vals(const float* __restrict__ grid, int q) {
    int a = q / APQ;
    int rem = q - a * APQ;
    int ex, ey, ez, q0, q1, q2, q3;
    float g0, g1;
    if (a == 0) {
        int i2 = rem % 160; int r = rem / 160; int i1 = r % 160; int i0 = r / 160;
        ex = i0; ey = i1 + 1; ez = i2 + 1;
        g0 = sampg(grid, ex, ey, ez);
        g1 = sampg(grid, ex + 1, ey, ez);
        int b = (ex * C + ey) * C + ez;
        q0 = b - C - 1; q1 = b - 1; q2 = b; q3 = b - C;
    } else if (a == 1) {
        int i2 = rem % 160; int r = rem / 160; int i1 = r % 161; int i0 = r / 161;
        ex = i0 + 1; ey = i1; ez = i2 + 1;
        g0 = sampg(grid, ex, ey, ez);
        g1 = sampg(grid, ex, ey + 1, ez);
        int b = (ex * C + ey) * C + ez;
        q0 = b - C * C - 1; q1 = b - 1; q2 = b; q3 = b - C * C;
    } else {
        int i2 = rem % 161; int r = rem / 161; int i1 = r % 160; int i0 = r / 160;
        ex = i0 + 1; ey = i1 + 1; ez = i2;
        g0 = sampg(grid, ex, ey, ez);
        g1 = sampg(grid, ex, ey, ez + 1);
        int b = (ex * C + ey) * C + ez;
        q0 = b - C * C - C; q1 = b - C; q2 = b; q3 = b - C * C;
    }
    float4 w;
    bool m = (g0 < 0.f) != (g1 < 0.f);
    if (!m) {
        w.x = w.y = w.z = w.w = -1.0f;
    } else {
        int a0, a1, a2, a3;
        if (g0 < 0.f) { a0 = q0; a1 = q1; a2 = q2; a3 = q3; }
        else          { a0 = q3; a1 = q2; a2 = q1; a3 = q0; }
        w.x = bf16r((float)a0);
        w.y = bf16r((float)a1);
        w.z = bf16r((float)a2);
        w.w = bf16r((float)a3);
    }
    return w;
}

__global__ __launch_bounds__(256) void quads_kernel(const float* __restrict__ grid,
                                                    float* __restrict__ out) {
    __shared__ __align__(16) float sq[1024];
    int b = blockIdx.x, t = threadIdx.x;
    int q = (b << 8) + t;
    float4 w = quad_vals(grid, q);
    // shifted window: lds[i] holds global element NVERT + 1 + 1024*b + i
    sq[(t << 2) + 0] = w.y;
    sq[(t << 2) + 1] = w.z;
    sq[(t << 2) + 2] = w.w;
    if (t > 0) sq[(t << 2) - 1] = w.x;
    if (t == 255) {
        int q2 = q + 1;
        if (q2 < TQ) {
            float4 w2 = quad_vals(grid, q2);
            sq[1023] = w2.x;
        }
    }
    if (b == 0 && t == 0) out[NVERT_ELEMS] = w.x;  // head element (quad0 elem0)

    __syncthreads();
    int avail = TOTQ_ELEMS - 1 - (b << 10);
    if (avail > 1024) avail = 1024;
    int off = t << 2;
    float* gp = out + NVERT_ELEMS + 1 + ((size_t)b << 10);
    if (off + 4 <= avail) {
        float4 v = *(const float4*)&sq[off];
        *(float4*)(gp + off) = v;
    } else if (off < avail) {
        for (int k = off; k < avail; ++k) gp[k] = sq[k];
    }
}

extern "C" void kernel_launch(void* const* d_in, const int* in_sizes, int n_in,
                              void* d_out, int out_size, void* d_ws, size_t ws_size,
                              hipStream_t stream) {
    const float* grid   = (const float*)d_in[0];
    const float* deform = (const float*)d_in[1];
    float* out = (float*)d_out;

    int nvb = (C3 + 255) / 256;   // 16302
    hipLaunchKernelGGL(verts_kernel, dim3(nvb), dim3(256), 0, stream, grid, deform, out);

    int nqb = TQ / 256;           // 48300 exact
    hipLaunchKernelGGL(quads_kernel, dim3(nqb), dim3(256), 0, stream, grid, out);
}